// Round 2
// baseline (514.169 us; speedup 1.0000x reference)
//
#include <hip/hip_runtime.h>
#include <hip/hip_bf16.h>
#include <math.h>

typedef float  f32x4 __attribute__((ext_vector_type(4)));
typedef _Float16 f16x8 __attribute__((ext_vector_type(8)));
typedef short  s16x8 __attribute__((ext_vector_type(8)));

// workspace byte offsets
#define WFWDT_OFF  0u        // float[128][16][16]  W_FWD^T: [k][l][m] (wq folded in)
#define PCTT_OFF   131072u   // float[128][16][16]  PCT_INV^T: [k][l][m]
#define FFRAG_OFF  262144u   // _Float16[8192] fwd DFT B-frags [kc(8)][nt(2)][lane][8]
#define TBFRAG_OFF 278528u   // _Float16[8192] inv DFT B-frags [wt(16)][lane][8]
#define Z_OFF      294912u   // bf16[64][4096]
#define H_OFF      819200u   // bf16[64][8192]
#define OH_OFF     1867776u  // float[64][4096]

static __device__ __forceinline__ float gelu_f(float v) {
  return 0.5f * v * (1.0f + erff(v * 0.70710678118654752f));
}
static __device__ __forceinline__ unsigned short f2bf(float a) {
  union { __hip_bfloat16 h; unsigned short u; } cv;
  cv.h = __float2bfloat16(a);
  return cv.u;
}
// pack two floats -> bf16x2 (lo = a, hi = b), RNE per element
static __device__ __forceinline__ unsigned int pack_bf2(float a, float b) {
  return (unsigned int)f2bf(a) | ((unsigned int)f2bf(b) << 16);
}

// ---------------- K0: constant tables (Legendre via DP recurrence + twiddles) ----
__global__ __launch_bounds__(256) void k0_tables(float* __restrict__ wfwdt,
    float* __restrict__ pctt, _Float16* __restrict__ ffrag, _Float16* __restrict__ tbfrag) {
  const int tid = threadIdx.x;
  const double PI = 3.14159265358979323846;
  if (tid < 128) {
    const int k = tid;
    const double xx = cos(PI * (double)(127 - k) / 127.0);  // ct[k]
    const double tj = PI * (double)k / 127.0;
    double wq = 2.0 / 127.0;
    for (int qq = 1; qq <= 63; ++qq)
      wq -= 2.0 * cos(2.0 * qq * tj) * (2.0 / 127.0) / (4.0 * (double)qq * qq - 1.0);
    if (k == 0 || k == 127) wq *= 0.5;

    double prev2[16], prev1[16], cur[16];
    double diag = 0.28209479177387814347;  // 1/sqrt(4pi)
    for (int m = 0; m < 16; ++m) { prev2[m] = 0.0; prev1[m] = 0.0; cur[m] = 0.0; }
    cur[0] = diag;
    for (int m = 0; m < 16; ++m) {
      double v = cur[m] * ((m & 1) ? -1.0 : 1.0);
      wfwdt[k*256 + m] = (float)(v * wq);
      pctt [k*256 + m] = (float)v;
      prev1[m] = cur[m];
    }
    for (int l = 1; l < 16; ++l) {
      double nd  = sqrt((2.0*l + 1.0) * (1.0 + xx) * (1.0 - xx) / (2.0 * l)) * diag;
      double sup = sqrt(2.0*l + 1.0) * xx * diag;
      for (int m = 0; m < 16; ++m) cur[m] = 0.0;
      for (int m = 0; m <= l - 2; ++m) {
        double a  = sqrt((2.0*l - 1.0)/(double)(l - m) * (2.0*l + 1.0)/(double)(l + m));
        double bb = sqrt(((double)l + m - 1.0)/(double)(l - m) * (2.0*l + 1.0)/(2.0*l - 3.0)
                         * ((double)l - m - 1.0)/(double)(l + m));
        cur[m] = a * xx * prev1[m] - bb * prev2[m];
      }
      cur[l-1] = sup;
      cur[l]   = nd;
      for (int m = 0; m < 16; ++m) {
        double v = cur[m] * ((m & 1) ? -1.0 : 1.0);
        wfwdt[k*256 + l*16 + m] = (float)(v * wq);
        pctt [k*256 + l*16 + m] = (float)v;
        prev2[m] = prev1[m]; prev1[m] = cur[m];
      }
      diag = nd;
    }
  }
  // twiddle tables, fragment-ordered
  const double S = 2.0 * PI / 256.0;
  for (int i = tid; i < 8192; i += 256) {
    const int j = i & 7, ln = (i >> 3) & 63, blk = i >> 9;
    {  // forward: F[w][kap], kap=2m(+1) -> (s*cos, -s*sin); B[k=w][n=kap]
      const int nt = blk & 1, kc = blk >> 1;
      const int w = kc*32 + (ln >> 4)*8 + j;
      const int kap = nt*16 + (ln & 15);
      const int m = kap >> 1;
      const double th = S * (double)((m * w) & 255);
      const double v = (kap & 1) ? (-S * sin(th)) : (S * cos(th));
      ffrag[i] = (_Float16)(float)v;
    }
    {  // inverse: TB[kap][w]; m=0: (1, 0); m>0: (2cos, -2sin)  [Im(X0) dropped like irfft]
      const int wt = blk;
      const int w = wt*16 + (ln & 15);
      const int kap = (ln >> 4)*8 + j;
      const int m = kap >> 1;
      const double th = S * (double)((m * w) & 255);
      double v;
      if (kap & 1) v = (m == 0) ? 0.0 : (-2.0 * sin(th));
      else         v = (m == 0) ? 1.0 : ( 2.0 * cos(th));
      tbfrag[i] = (_Float16)(float)v;
    }
  }
}

// ---------------- K1: forward transform  x[b,c] -> z[b, c*512 + l*32 + 2m+ri] ----
__global__ __launch_bounds__(256) void k1_fwd(const float* __restrict__ x,
    const float* __restrict__ wfwdt, const _Float16* __restrict__ ffrag,
    unsigned short* __restrict__ z) {
  __shared__ _Float16 sF[8192];
  __shared__ float sxf[128 * 34];  // xf[k][kap], stride 34 (pad)
  const int tid = threadIdx.x;
  const int lane = tid & 63, wv = tid >> 6;
  const int n = lane & 15, q = lane >> 4;
  const int bc = blockIdx.x;
  {
    const uint4* src = (const uint4*)ffrag;
    uint4* dst = (uint4*)sF;
    for (int i = tid; i < 1024; i += 256) dst[i] = src[i];
  }
  __syncthreads();
  f32x4 acc[2][2];
  for (int a1 = 0; a1 < 2; ++a1) for (int a2 = 0; a2 < 2; ++a2)
    acc[a1][a2] = (f32x4){0.f, 0.f, 0.f, 0.f};
  const float* xb = x + (size_t)bc * 32768;
  for (int kc = 0; kc < 8; ++kc) {
    f16x8 bfr0 = *(const f16x8*)&sF[((kc*2 + 0)*64 + lane)*8];
    f16x8 bfr1 = *(const f16x8*)&sF[((kc*2 + 1)*64 + lane)*8];
#pragma unroll
    for (int rtl = 0; rtl < 2; ++rtl) {
      const int row = (2*wv + rtl)*16 + n;
      const float* p = xb + row*256 + kc*32 + q*8;
      f32x4 v0 = *(const f32x4*)p;
      f32x4 v1 = *(const f32x4*)(p + 4);
      f16x8 afr;
      afr[0] = (_Float16)v0.x; afr[1] = (_Float16)v0.y;
      afr[2] = (_Float16)v0.z; afr[3] = (_Float16)v0.w;
      afr[4] = (_Float16)v1.x; afr[5] = (_Float16)v1.y;
      afr[6] = (_Float16)v1.z; afr[7] = (_Float16)v1.w;
      acc[rtl][0] = __builtin_amdgcn_mfma_f32_16x16x32_f16(afr, bfr0, acc[rtl][0], 0, 0, 0);
      acc[rtl][1] = __builtin_amdgcn_mfma_f32_16x16x32_f16(afr, bfr1, acc[rtl][1], 0, 0, 0);
    }
  }
#pragma unroll
  for (int rtl = 0; rtl < 2; ++rtl)
#pragma unroll
    for (int nt = 0; nt < 2; ++nt)
#pragma unroll
      for (int r = 0; r < 4; ++r)
        sxf[((2*wv + rtl)*16 + q*4 + r)*34 + nt*16 + n] = acc[rtl][nt][r];
  __syncthreads();
  // stage 2: contract over k with W_FWD
  const int m = tid & 15, l = tid >> 4;
  float zre = 0.f, zim = 0.f;
  const float* wp = wfwdt + l*16 + m;
#pragma unroll 4
  for (int k = 0; k < 128; ++k) {
    const float wk = wp[k*256];
    zre += wk * sxf[k*34 + 2*m];
    zim += wk * sxf[k*34 + 2*m + 1];
  }
  const int b = bc >> 3, c = bc & 7;
  *(unsigned int*)&z[(size_t)b*4096 + c*512 + l*32 + 2*m] = pack_bf2(zre, zim);
}

// ---------------- K2: h = gelu(z @ w0^T + b0), bf16 MFMA, weights streamed ------
__global__ __launch_bounds__(256) void k2_mlp1(const unsigned short* __restrict__ z,
    const float* __restrict__ w0, const float* __restrict__ bias0,
    unsigned short* __restrict__ h) {
  __shared__ short sB[8192];  // bf16 frags [s(8)][nt(2)][lane][8]
  const int tid = threadIdx.x, lane = tid & 63, wv = tid >> 6;
  const int n = lane & 15, q = lane >> 4;
  const int h0 = blockIdx.x * 32;
  int se[4]; size_t sgl[4];
#pragma unroll
  for (int i = 0; i < 4; ++i) {
    const int e = i*256 + tid;
    const int blk = e >> 6, ls = e & 63;
    const int s = blk >> 1, nt = blk & 1;
    se[i] = e;
    sgl[i] = (size_t)(h0 + nt*16 + (ls & 15))*4096 + s*32 + (ls >> 4)*8;
  }
  f32x4 pfa[4], pfb[4];
#pragma unroll
  for (int i = 0; i < 4; ++i) {
    const float* p = &w0[sgl[i]];
    pfa[i] = *(const f32x4*)p; pfb[i] = *(const f32x4*)(p + 4);
  }
  f32x4 acc0 = {0.f,0.f,0.f,0.f}, acc1 = {0.f,0.f,0.f,0.f};
  const unsigned short* zp = z + (size_t)(wv*16 + n)*4096 + q*8;
  for (int kc = 0; kc < 16; ++kc) {
    __syncthreads();
#pragma unroll
    for (int i = 0; i < 4; ++i) {
      union { unsigned int u[4]; uint4 v; } pk;
      pk.u[0] = pack_bf2(pfa[i].x, pfa[i].y);
      pk.u[1] = pack_bf2(pfa[i].z, pfa[i].w);
      pk.u[2] = pack_bf2(pfb[i].x, pfb[i].y);
      pk.u[3] = pack_bf2(pfb[i].z, pfb[i].w);
      *(uint4*)&sB[se[i]*8] = pk.v;
    }
    __syncthreads();
    if (kc < 15) {
#pragma unroll
      for (int i = 0; i < 4; ++i) {
        const float* p = &w0[sgl[i] + (size_t)(kc + 1)*256];
        pfa[i] = *(const f32x4*)p; pfb[i] = *(const f32x4*)(p + 4);
      }
    }
#pragma unroll
    for (int s = 0; s < 8; ++s) {
      s16x8 afr = *(const s16x8*)(zp + (size_t)kc*256 + s*32);
      s16x8 bf0 = *(const s16x8*)&sB[((s*2 + 0)*64 + lane)*8];
      s16x8 bf1 = *(const s16x8*)&sB[((s*2 + 1)*64 + lane)*8];
      acc0 = __builtin_amdgcn_mfma_f32_16x16x32_bf16(afr, bf0, acc0, 0, 0, 0);
      acc1 = __builtin_amdgcn_mfma_f32_16x16x32_bf16(afr, bf1, acc1, 0, 0, 0);
    }
  }
#pragma unroll
  for (int nt = 0; nt < 2; ++nt) {
    f32x4 a = nt ? acc1 : acc0;
    const int col = h0 + nt*16 + n;
    const float bias = bias0[col];
#pragma unroll
    for (int r = 0; r < 4; ++r) {
      const int row = wv*16 + q*4 + r;
      h[(size_t)row*8192 + col] = f2bf(gelu_f(a[r] + bias));
    }
  }
}

// ---------------- K3: oh = h @ w1^T (fp32 out) -----------------------------------
__global__ __launch_bounds__(256) void k3_mlp2(const unsigned short* __restrict__ h,
    const float* __restrict__ w1, float* __restrict__ oh) {
  __shared__ short sB[4096];  // [s(8)][lane][8]
  const int tid = threadIdx.x, lane = tid & 63, wv = tid >> 6;
  const int n = lane & 15, q = lane >> 4;
  const int j0 = blockIdx.x * 16;
  int se[2]; size_t sgl[2];
#pragma unroll
  for (int i = 0; i < 2; ++i) {
    const int e = i*256 + tid;
    const int s = e >> 6, ls = e & 63;
    se[i] = e;
    sgl[i] = (size_t)(j0 + (ls & 15))*8192 + s*32 + (ls >> 4)*8;
  }
  f32x4 pfa[2], pfb[2];
#pragma unroll
  for (int i = 0; i < 2; ++i) {
    const float* p = &w1[sgl[i]];
    pfa[i] = *(const f32x4*)p; pfb[i] = *(const f32x4*)(p + 4);
  }
  f32x4 acc = {0.f,0.f,0.f,0.f};
  const unsigned short* hp = h + (size_t)(wv*16 + n)*8192 + q*8;
  for (int kc = 0; kc < 32; ++kc) {
    __syncthreads();
#pragma unroll
    for (int i = 0; i < 2; ++i) {
      union { unsigned int u[4]; uint4 v; } pk;
      pk.u[0] = pack_bf2(pfa[i].x, pfa[i].y);
      pk.u[1] = pack_bf2(pfa[i].z, pfa[i].w);
      pk.u[2] = pack_bf2(pfb[i].x, pfb[i].y);
      pk.u[3] = pack_bf2(pfb[i].z, pfb[i].w);
      *(uint4*)&sB[se[i]*8] = pk.v;
    }
    __syncthreads();
    if (kc < 31) {
#pragma unroll
      for (int i = 0; i < 2; ++i) {
        const float* p = &w1[sgl[i] + (size_t)(kc + 1)*256];
        pfa[i] = *(const f32x4*)p; pfb[i] = *(const f32x4*)(p + 4);
      }
    }
#pragma unroll
    for (int s = 0; s < 8; ++s) {
      s16x8 afr = *(const s16x8*)(hp + (size_t)kc*256 + s*32);
      s16x8 bfr = *(const s16x8*)&sB[(s*64 + lane)*8];
      acc = __builtin_amdgcn_mfma_f32_16x16x32_bf16(afr, bfr, acc, 0, 0, 0);
    }
  }
#pragma unroll
  for (int r = 0; r < 4; ++r)
    oh[(size_t)(wv*16 + q*4 + r)*4096 + j0 + n] = acc[r];
}

// ---------------- K4: inverse transform + bypass + gelu -> out -------------------
__global__ __launch_bounds__(256) void k4_inv(const float* __restrict__ oh,
    const float* __restrict__ pctt, const _Float16* __restrict__ tbfrag,
    const float* __restrict__ x, const float* __restrict__ cw,
    const float* __restrict__ cb, float* __restrict__ out) {
  __shared__ float soh[4096];
  __shared__ float spct[4096];
  __shared__ _Float16 sTB[8192];
  __shared__ _Float16 sXK[128 * 40];  // [row=(c,kk)][kap], stride 40 (pad)
  __shared__ float scw[64];
  __shared__ float scb[8];
  const int tid = threadIdx.x, lane = tid & 63, wv = tid >> 6;
  const int n = lane & 15, q = lane >> 4;
  const int b = blockIdx.x >> 3, k0 = (blockIdx.x & 7) * 16;
  {
    const f32x4* s1 = (const f32x4*)(oh + (size_t)b*4096);
    const f32x4* s2 = (const f32x4*)(pctt + (size_t)k0*256);
    const uint4* s3 = (const uint4*)tbfrag;
    for (int i = tid; i < 1024; i += 256) {
      ((f32x4*)soh)[i]  = s1[i];
      ((f32x4*)spct)[i] = s2[i];
      ((uint4*)sTB)[i]  = s3[i];
    }
    if (tid < 64) scw[tid] = cw[tid];
    if (tid < 8)  scb[tid] = cb[tid];
  }
  __syncthreads();
  // XK[c*16+kk][2m+ri] = sum_l oh[c,l,m,ri] * PCT[kk][l][m]
#pragma unroll
  for (int i = 0; i < 8; ++i) {
    const int p = i*256 + tid;
    const int row = p >> 4, m = p & 15;
    const int cc = row >> 4, kk = row & 15;
    float re = 0.f, im = 0.f;
    const float* op = soh + cc*512 + m*2;
    const float* pp = spct + kk*256 + m;
#pragma unroll
    for (int l = 0; l < 16; ++l) {
      const float pv = pp[l*16];
      re += pv * op[l*32];
      im += pv * op[l*32 + 1];
    }
    sXK[row*40 + 2*m]     = (_Float16)re;
    sXK[row*40 + 2*m + 1] = (_Float16)im;
  }
  __syncthreads();
  const f16x8 afr0 = *(const f16x8*)&sXK[((2*wv + 0)*16 + n)*40 + q*8];
  const f16x8 afr1 = *(const f16x8*)&sXK[((2*wv + 1)*16 + n)*40 + q*8];
  float cw0[8], cw1[8];
#pragma unroll
  for (int ci = 0; ci < 8; ++ci) {
    cw0[ci] = scw[(2*wv + 0)*8 + ci];
    cw1[ci] = scw[(2*wv + 1)*8 + ci];
  }
  const float cb0 = scb[2*wv], cb1 = scb[2*wv + 1];
  for (int wt = 0; wt < 16; ++wt) {
    const f16x8 bfr = *(const f16x8*)&sTB[(wt*64 + lane)*8];
    f32x4 z4 = {0.f,0.f,0.f,0.f};
    f32x4 a0 = __builtin_amdgcn_mfma_f32_16x16x32_f16(afr0, bfr, z4, 0, 0, 0);
    f32x4 a1 = __builtin_amdgcn_mfma_f32_16x16x32_f16(afr1, bfr, z4, 0, 0, 0);
    const int w = wt*16 + n;
    float bp0[4] = {0.f,0.f,0.f,0.f}, bp1[4] = {0.f,0.f,0.f,0.f};
    const float* xp = x + ((size_t)b*1024 + (size_t)(k0 + q*4))*256 + w;
#pragma unroll
    for (int ci = 0; ci < 8; ++ci) {
      const float* xq = xp + (size_t)ci*32768;
      const float c0 = cw0[ci], c1 = cw1[ci];
#pragma unroll
      for (int r = 0; r < 4; ++r) {
        const float xv = xq[r*256];
        bp0[r] += xv * c0;
        bp1[r] += xv * c1;
      }
    }
    float* op0 = out + (((size_t)b*8 + 2*wv + 0)*128 + k0 + q*4)*256 + w;
    float* op1 = out + (((size_t)b*8 + 2*wv + 1)*128 + k0 + q*4)*256 + w;
#pragma unroll
    for (int r = 0; r < 4; ++r) {
      op0[r*256] = gelu_f(a0[r] + bp0[r] + cb0);
      op1[r*256] = gelu_f(a1[r] + bp1[r] + cb1);
    }
  }
}

extern "C" void kernel_launch(void* const* d_in, const int* in_sizes, int n_in,
                              void* d_out, int out_size, void* d_ws, size_t ws_size,
                              hipStream_t stream) {
  (void)in_sizes; (void)n_in; (void)out_size; (void)ws_size;
  const float* x   = (const float*)d_in[0];
  const float* w0  = (const float*)d_in[1];
  const float* b0v = (const float*)d_in[2];
  const float* w1  = (const float*)d_in[3];
  const float* cw  = (const float*)d_in[4];
  const float* cb  = (const float*)d_in[5];
  float* out = (float*)d_out;
  char* ws = (char*)d_ws;
  float* wfwdt        = (float*)(ws + WFWDT_OFF);
  float* pctt         = (float*)(ws + PCTT_OFF);
  _Float16* ffrag     = (_Float16*)(ws + FFRAG_OFF);
  _Float16* tbfr      = (_Float16*)(ws + TBFRAG_OFF);
  unsigned short* z   = (unsigned short*)(ws + Z_OFF);
  unsigned short* h   = (unsigned short*)(ws + H_OFF);
  float* oh           = (float*)(ws + OH_OFF);

  hipLaunchKernelGGL(k0_tables, dim3(1),   dim3(256), 0, stream, wfwdt, pctt, ffrag, tbfr);
  hipLaunchKernelGGL(k1_fwd,    dim3(512), dim3(256), 0, stream, x, wfwdt, ffrag, z);
  hipLaunchKernelGGL(k2_mlp1,   dim3(256), dim3(256), 0, stream, z, w0, b0v, h);
  hipLaunchKernelGGL(k3_mlp2,   dim3(256), dim3(256), 0, stream, h, w1, oh);
  hipLaunchKernelGGL(k4_inv,    dim3(512), dim3(256), 0, stream, oh, pctt, tbfr, x, cw, cb, out);
}

// Round 3
// 435.369 us; speedup vs baseline: 1.1810x; 1.1810x over previous
//
#include <hip/hip_runtime.h>
#include <hip/hip_bf16.h>
#include <math.h>

typedef float  f32x4 __attribute__((ext_vector_type(4)));
typedef _Float16 f16x8 __attribute__((ext_vector_type(8)));
typedef short  s16x8 __attribute__((ext_vector_type(8)));

// workspace byte offsets
#define WFWDT_OFF  0u        // float[128][16][16]  W_FWD^T: [k][l][m] (wq folded in)
#define PCTT_OFF   131072u   // float[128][16][16]  PCT_INV^T: [k][l][m]
#define FFRAG_OFF  262144u   // _Float16[8192] fwd DFT B-frags [kc(8)][nt(2)][lane][8]
#define TBFRAG_OFF 278528u   // _Float16[8192] inv DFT B-frags [wt(16)][lane][8]
#define Z_OFF      294912u   // bf16[64][4096]
#define H_OFF      819200u   // bf16[64][8192]
#define OH_OFF     1867776u  // float[64][4096] partial 0
#define OH1_OFF    2916352u  // float[64][4096] partial 1

static __device__ __forceinline__ float gelu_f(float v) {
  return 0.5f * v * (1.0f + erff(v * 0.70710678118654752f));
}
static __device__ __forceinline__ unsigned short f2bf(float a) {
  union { __hip_bfloat16 h; unsigned short u; } cv;
  cv.h = __float2bfloat16(a);
  return cv.u;
}
// pack two floats -> bf16x2 (lo = a, hi = b), RNE per element
static __device__ __forceinline__ unsigned int pack_bf2(float a, float b) {
  return (unsigned int)f2bf(a) | ((unsigned int)f2bf(b) << 16);
}

// ---------------- K0: constant tables.  block 0: Legendre; block 1: twiddles ----
__global__ __launch_bounds__(256) void k0_tables(float* __restrict__ wfwdt,
    float* __restrict__ pctt, _Float16* __restrict__ ffrag, _Float16* __restrict__ tbfrag) {
  const int tid = threadIdx.x;
  const double PI = 3.14159265358979323846;
  if (blockIdx.x == 1) {
    // -------- twiddle tables via 256-entry sincos LUT (angles are (m*w)&255) ----
    __shared__ float lc[256], ls2[256];
    {
      const double th = 2.0 * PI * (double)tid / 256.0;
      lc[tid]  = (float)cos(th);
      ls2[tid] = (float)sin(th);
    }
    __syncthreads();
    const float S = (float)(2.0 * PI / 256.0);
    for (int i = tid; i < 8192; i += 256) {
      const int j = i & 7, ln = (i >> 3) & 63, blk = i >> 9;
      {  // forward: B[k=w][n=kap], kap=2m(+1) -> (S*cos, -S*sin)
        const int nt = blk & 1, kc = blk >> 1;
        const int w = kc*32 + (ln >> 4)*8 + j;
        const int kap = nt*16 + (ln & 15);
        const int m = kap >> 1;
        const int a = (m * w) & 255;
        const float v = (kap & 1) ? (-S * ls2[a]) : (S * lc[a]);
        ffrag[i] = (_Float16)v;
      }
      {  // inverse: TB[kap][w]; m=0: (1,0); m>0: (2cos,-2sin)
        const int wt = blk;
        const int w = wt*16 + (ln & 15);
        const int kap = (ln >> 4)*8 + j;
        const int m = kap >> 1;
        const int a = (m * w) & 255;
        float v;
        if (kap & 1) v = (m == 0) ? 0.0f : (-2.0f * ls2[a]);
        else         v = (m == 0) ? 1.0f : ( 2.0f * lc[a]);
        tbfrag[i] = (_Float16)v;
      }
    }
    return;
  }
  // -------- block 0: Legendre tables ------------------------------------------
  __shared__ double cA[256], cB[256];  // recurrence coeffs a(l,m), b(l,m)
  {
    const int l = tid >> 4, m = tid & 15;
    double a = 0.0, bb = 0.0;
    if (l >= 2 && m <= l - 2) {
      a  = sqrt((2.0*l - 1.0)/(double)(l - m) * (2.0*l + 1.0)/(double)(l + m));
      bb = sqrt(((double)l + m - 1.0)/(double)(l - m) * (2.0*l + 1.0)/(2.0*l - 3.0)
                * ((double)l - m - 1.0)/(double)(l + m));
    }
    cA[tid] = a; cB[tid] = bb;
  }
  __syncthreads();
  if (tid >= 128) return;
  const int k = tid;
  const double xx = cos(PI * (double)(127 - k) / 127.0);  // ct[k]
  const double tj = PI * (double)k / 127.0;
  // CC weights via Chebyshev recurrence: c_q = cos(2 q tj)
  double wq = 2.0 / 127.0;
  {
    const double t2 = cos(2.0 * tj);
    double cm1 = 1.0, c = t2;
    for (int qq = 1; qq <= 63; ++qq) {
      wq -= 2.0 * c * (2.0 / 127.0) / (4.0 * (double)qq * qq - 1.0);
      const double cn = 2.0 * t2 * c - cm1;
      cm1 = c; c = cn;
    }
    if (k == 0 || k == 127) wq *= 0.5;
  }
  double prev2[16], prev1[16], cur[16];
  double diag = 0.28209479177387814347;  // 1/sqrt(4pi)
  for (int m = 0; m < 16; ++m) { prev2[m] = 0.0; prev1[m] = 0.0; }
  cur[0] = diag;
  for (int m = 1; m < 16; ++m) cur[m] = 0.0;
  for (int m = 0; m < 16; ++m) {
    double v = cur[m] * ((m & 1) ? -1.0 : 1.0);
    wfwdt[k*256 + m] = (float)(v * wq);
    pctt [k*256 + m] = (float)v;
    prev1[m] = cur[m];
  }
  for (int l = 1; l < 16; ++l) {
    const double nd  = sqrt((2.0*l + 1.0) * (1.0 + xx) * (1.0 - xx) / (2.0 * l)) * diag;
    const double sup = sqrt(2.0*l + 1.0) * xx * diag;
    for (int m = 0; m < 16; ++m) cur[m] = 0.0;
    for (int m = 0; m <= l - 2; ++m)
      cur[m] = cA[l*16 + m] * xx * prev1[m] - cB[l*16 + m] * prev2[m];
    cur[l-1] = sup;
    cur[l]   = nd;
    for (int m = 0; m < 16; ++m) {
      double v = cur[m] * ((m & 1) ? -1.0 : 1.0);
      wfwdt[k*256 + l*16 + m] = (float)(v * wq);
      pctt [k*256 + l*16 + m] = (float)v;
      prev2[m] = prev1[m]; prev1[m] = cur[m];
    }
    diag = nd;
  }
}

// ---------------- K1: forward transform  x[b,c] -> z[b, c*512 + l*32 + 2m+ri] ----
__global__ __launch_bounds__(256) void k1_fwd(const float* __restrict__ x,
    const float* __restrict__ wfwdt, const _Float16* __restrict__ ffrag,
    unsigned short* __restrict__ z) {
  __shared__ _Float16 sF[8192];
  __shared__ float sxf[128 * 34];  // xf[k][kap], stride 34 (pad)
  const int tid = threadIdx.x;
  const int lane = tid & 63, wv = tid >> 6;
  const int n = lane & 15, q = lane >> 4;
  const int bc = blockIdx.x;
  {
    const uint4* src = (const uint4*)ffrag;
    uint4* dst = (uint4*)sF;
    for (int i = tid; i < 1024; i += 256) dst[i] = src[i];
  }
  __syncthreads();
  f32x4 acc[2][2];
  for (int a1 = 0; a1 < 2; ++a1) for (int a2 = 0; a2 < 2; ++a2)
    acc[a1][a2] = (f32x4){0.f, 0.f, 0.f, 0.f};
  const float* xb = x + (size_t)bc * 32768;
  for (int kc = 0; kc < 8; ++kc) {
    f16x8 bfr0 = *(const f16x8*)&sF[((kc*2 + 0)*64 + lane)*8];
    f16x8 bfr1 = *(const f16x8*)&sF[((kc*2 + 1)*64 + lane)*8];
#pragma unroll
    for (int rtl = 0; rtl < 2; ++rtl) {
      const int row = (2*wv + rtl)*16 + n;
      const float* p = xb + row*256 + kc*32 + q*8;
      f32x4 v0 = *(const f32x4*)p;
      f32x4 v1 = *(const f32x4*)(p + 4);
      f16x8 afr;
      afr[0] = (_Float16)v0.x; afr[1] = (_Float16)v0.y;
      afr[2] = (_Float16)v0.z; afr[3] = (_Float16)v0.w;
      afr[4] = (_Float16)v1.x; afr[5] = (_Float16)v1.y;
      afr[6] = (_Float16)v1.z; afr[7] = (_Float16)v1.w;
      acc[rtl][0] = __builtin_amdgcn_mfma_f32_16x16x32_f16(afr, bfr0, acc[rtl][0], 0, 0, 0);
      acc[rtl][1] = __builtin_amdgcn_mfma_f32_16x16x32_f16(afr, bfr1, acc[rtl][1], 0, 0, 0);
    }
  }
#pragma unroll
  for (int rtl = 0; rtl < 2; ++rtl)
#pragma unroll
    for (int nt = 0; nt < 2; ++nt)
#pragma unroll
      for (int r = 0; r < 4; ++r)
        sxf[((2*wv + rtl)*16 + q*4 + r)*34 + nt*16 + n] = acc[rtl][nt][r];
  __syncthreads();
  // stage 2: contract over k with W_FWD
  const int m = tid & 15, l = tid >> 4;
  float zre = 0.f, zim = 0.f;
  const float* wp = wfwdt + l*16 + m;
#pragma unroll 4
  for (int k = 0; k < 128; ++k) {
    const float wk = wp[k*256];
    zre += wk * sxf[k*34 + 2*m];
    zim += wk * sxf[k*34 + 2*m + 1];
  }
  const int b = bc >> 3, c = bc & 7;
  *(unsigned int*)&z[(size_t)b*4096 + c*512 + l*32 + 2*m] = pack_bf2(zre, zim);
}

// ---------------- K2: h = gelu(z @ w0^T + b0); 16 cols/block, depth-2 prefetch --
__global__ __launch_bounds__(256) void k2_mlp1(const unsigned short* __restrict__ z,
    const float* __restrict__ w0, const float* __restrict__ bias0,
    unsigned short* __restrict__ h) {
  __shared__ short sB[4096];  // bf16 frags [s(8)][lane][8] for one 256-k chunk
  const int tid = threadIdx.x, lane = tid & 63, wv = tid >> 6;
  const int n = lane & 15, q = lane >> 4;
  const int h0 = blockIdx.x * 16;
  int se[2]; size_t sgl[2];
#pragma unroll
  for (int i = 0; i < 2; ++i) {
    const int e = i*256 + tid;
    const int s = e >> 6, ls = e & 63;
    se[i] = e;
    sgl[i] = (size_t)(h0 + (ls & 15))*4096 + s*32 + (ls >> 4)*8;
  }
  f32x4 pfa[2][2], pfb[2][2];
#pragma unroll
  for (int d = 0; d < 2; ++d)
#pragma unroll
    for (int i = 0; i < 2; ++i) {
      const float* p = &w0[sgl[i] + (size_t)d*256];
      pfa[d][i] = *(const f32x4*)p; pfb[d][i] = *(const f32x4*)(p + 4);
    }
  f32x4 acc = {0.f,0.f,0.f,0.f};
  const unsigned short* zp = z + (size_t)(wv*16 + n)*4096 + q*8;
  for (int kc = 0; kc < 16; ++kc) {
    const int pp = kc & 1;
    __syncthreads();
#pragma unroll
    for (int i = 0; i < 2; ++i) {
      union { unsigned int u[4]; uint4 v; } pk;
      pk.u[0] = pack_bf2(pfa[pp][i].x, pfa[pp][i].y);
      pk.u[1] = pack_bf2(pfa[pp][i].z, pfa[pp][i].w);
      pk.u[2] = pack_bf2(pfb[pp][i].x, pfb[pp][i].y);
      pk.u[3] = pack_bf2(pfb[pp][i].z, pfb[pp][i].w);
      *(uint4*)&sB[se[i]*8] = pk.v;
    }
    __syncthreads();
    if (kc < 14) {
#pragma unroll
      for (int i = 0; i < 2; ++i) {
        const float* p = &w0[sgl[i] + (size_t)(kc + 2)*256];
        pfa[pp][i] = *(const f32x4*)p; pfb[pp][i] = *(const f32x4*)(p + 4);
      }
    }
#pragma unroll
    for (int s = 0; s < 8; ++s) {
      s16x8 afr = *(const s16x8*)(zp + (size_t)kc*256 + s*32);
      s16x8 bfr = *(const s16x8*)&sB[(s*64 + lane)*8];
      acc = __builtin_amdgcn_mfma_f32_16x16x32_bf16(afr, bfr, acc, 0, 0, 0);
    }
  }
  const int col = h0 + n;
  const float bias = bias0[col];
#pragma unroll
  for (int r = 0; r < 4; ++r) {
    const int row = wv*16 + q*4 + r;
    h[(size_t)row*8192 + col] = f2bf(gelu_f(acc[r] + bias));
  }
}

// ---------------- K3: oh_kh = h[:,kh] @ w1[:,kh]^T; K split in 2 halves ---------
__global__ __launch_bounds__(256) void k3_mlp2(const unsigned short* __restrict__ h,
    const float* __restrict__ w1, float* __restrict__ oh0, float* __restrict__ oh1) {
  __shared__ short sB[4096];  // [s(8)][lane][8]
  const int tid = threadIdx.x, lane = tid & 63, wv = tid >> 6;
  const int n = lane & 15, q = lane >> 4;
  const int j0 = (blockIdx.x >> 1) * 16;
  const int kh = blockIdx.x & 1;
  const size_t kbase = (size_t)kh * 4096;
  int se[2]; size_t sgl[2];
#pragma unroll
  for (int i = 0; i < 2; ++i) {
    const int e = i*256 + tid;
    const int s = e >> 6, ls = e & 63;
    se[i] = e;
    sgl[i] = (size_t)(j0 + (ls & 15))*8192 + kbase + s*32 + (ls >> 4)*8;
  }
  f32x4 pfa[2][2], pfb[2][2];
#pragma unroll
  for (int d = 0; d < 2; ++d)
#pragma unroll
    for (int i = 0; i < 2; ++i) {
      const float* p = &w1[sgl[i] + (size_t)d*256];
      pfa[d][i] = *(const f32x4*)p; pfb[d][i] = *(const f32x4*)(p + 4);
    }
  f32x4 acc = {0.f,0.f,0.f,0.f};
  const unsigned short* hp = h + (size_t)(wv*16 + n)*8192 + kbase + q*8;
  for (int kc = 0; kc < 16; ++kc) {
    const int pp = kc & 1;
    __syncthreads();
#pragma unroll
    for (int i = 0; i < 2; ++i) {
      union { unsigned int u[4]; uint4 v; } pk;
      pk.u[0] = pack_bf2(pfa[pp][i].x, pfa[pp][i].y);
      pk.u[1] = pack_bf2(pfa[pp][i].z, pfa[pp][i].w);
      pk.u[2] = pack_bf2(pfb[pp][i].x, pfb[pp][i].y);
      pk.u[3] = pack_bf2(pfb[pp][i].z, pfb[pp][i].w);
      *(uint4*)&sB[se[i]*8] = pk.v;
    }
    __syncthreads();
    if (kc < 14) {
#pragma unroll
      for (int i = 0; i < 2; ++i) {
        const float* p = &w1[sgl[i] + (size_t)(kc + 2)*256];
        pfa[pp][i] = *(const f32x4*)p; pfb[pp][i] = *(const f32x4*)(p + 4);
      }
    }
#pragma unroll
    for (int s = 0; s < 8; ++s) {
      s16x8 afr = *(const s16x8*)(hp + (size_t)kc*256 + s*32);
      s16x8 bfr = *(const s16x8*)&sB[(s*64 + lane)*8];
      acc = __builtin_amdgcn_mfma_f32_16x16x32_bf16(afr, bfr, acc, 0, 0, 0);
    }
  }
  float* ohp = kh ? oh1 : oh0;
#pragma unroll
  for (int r = 0; r < 4; ++r)
    ohp[(size_t)(wv*16 + q*4 + r)*4096 + j0 + n] = acc[r];
}

// ---------------- K4: inverse transform + bypass + gelu -> out -------------------
__global__ __launch_bounds__(256) void k4_inv(const float* __restrict__ oh0,
    const float* __restrict__ oh1,
    const float* __restrict__ pctt, const _Float16* __restrict__ tbfrag,
    const float* __restrict__ x, const float* __restrict__ cw,
    const float* __restrict__ cb, float* __restrict__ out) {
  __shared__ float soh[4096];
  __shared__ float spct[4096];
  __shared__ _Float16 sTB[8192];
  __shared__ _Float16 sXK[128 * 40];  // [row=(c,kk)][kap], stride 40 (pad)
  __shared__ float scw[64];
  __shared__ float scb[8];
  const int tid = threadIdx.x, lane = tid & 63, wv = tid >> 6;
  const int n = lane & 15, q = lane >> 4;
  const int b = blockIdx.x >> 3, k0 = (blockIdx.x & 7) * 16;
  {
    const f32x4* s1a = (const f32x4*)(oh0 + (size_t)b*4096);
    const f32x4* s1b = (const f32x4*)(oh1 + (size_t)b*4096);
    const f32x4* s2 = (const f32x4*)(pctt + (size_t)k0*256);
    const uint4* s3 = (const uint4*)tbfrag;
    for (int i = tid; i < 1024; i += 256) {
      f32x4 va = s1a[i], vb = s1b[i];
      ((f32x4*)soh)[i]  = va + vb;
      ((f32x4*)spct)[i] = s2[i];
      ((uint4*)sTB)[i]  = s3[i];
    }
    if (tid < 64) scw[tid] = cw[tid];
    if (tid < 8)  scb[tid] = cb[tid];
  }
  __syncthreads();
  // XK[c*16+kk][2m+ri] = sum_l oh[c,l,m,ri] * PCT[kk][l][m]
#pragma unroll
  for (int i = 0; i < 8; ++i) {
    const int p = i*256 + tid;
    const int row = p >> 4, m = p & 15;
    const int cc = row >> 4, kk = row & 15;
    float re = 0.f, im = 0.f;
    const float* op = soh + cc*512 + m*2;
    const float* pp = spct + kk*256 + m;
#pragma unroll
    for (int l = 0; l < 16; ++l) {
      const float pv = pp[l*16];
      re += pv * op[l*32];
      im += pv * op[l*32 + 1];
    }
    sXK[row*40 + 2*m]     = (_Float16)re;
    sXK[row*40 + 2*m + 1] = (_Float16)im;
  }
  __syncthreads();
  const f16x8 afr0 = *(const f16x8*)&sXK[((2*wv + 0)*16 + n)*40 + q*8];
  const f16x8 afr1 = *(const f16x8*)&sXK[((2*wv + 1)*16 + n)*40 + q*8];
  float cw0[8], cw1[8];
#pragma unroll
  for (int ci = 0; ci < 8; ++ci) {
    cw0[ci] = scw[(2*wv + 0)*8 + ci];
    cw1[ci] = scw[(2*wv + 1)*8 + ci];
  }
  const float cb0 = scb[2*wv], cb1 = scb[2*wv + 1];
  for (int wt = 0; wt < 16; ++wt) {
    const f16x8 bfr = *(const f16x8*)&sTB[(wt*64 + lane)*8];
    f32x4 z4 = {0.f,0.f,0.f,0.f};
    f32x4 a0 = __builtin_amdgcn_mfma_f32_16x16x32_f16(afr0, bfr, z4, 0, 0, 0);
    f32x4 a1 = __builtin_amdgcn_mfma_f32_16x16x32_f16(afr1, bfr, z4, 0, 0, 0);
    const int w = wt*16 + n;
    float bp0[4] = {0.f,0.f,0.f,0.f}, bp1[4] = {0.f,0.f,0.f,0.f};
    const float* xp = x + ((size_t)b*1024 + (size_t)(k0 + q*4))*256 + w;
#pragma unroll
    for (int ci = 0; ci < 8; ++ci) {
      const float* xq = xp + (size_t)ci*32768;
      const float c0 = cw0[ci], c1 = cw1[ci];
#pragma unroll
      for (int r = 0; r < 4; ++r) {
        const float xv = xq[r*256];
        bp0[r] += xv * c0;
        bp1[r] += xv * c1;
      }
    }
    float* op0 = out + (((size_t)b*8 + 2*wv + 0)*128 + k0 + q*4)*256 + w;
    float* op1 = out + (((size_t)b*8 + 2*wv + 1)*128 + k0 + q*4)*256 + w;
#pragma unroll
    for (int r = 0; r < 4; ++r) {
      op0[r*256] = gelu_f(a0[r] + bp0[r] + cb0);
      op1[r*256] = gelu_f(a1[r] + bp1[r] + cb1);
    }
  }
}

extern "C" void kernel_launch(void* const* d_in, const int* in_sizes, int n_in,
                              void* d_out, int out_size, void* d_ws, size_t ws_size,
                              hipStream_t stream) {
  (void)in_sizes; (void)n_in; (void)out_size; (void)ws_size;
  const float* x   = (const float*)d_in[0];
  const float* w0  = (const float*)d_in[1];
  const float* b0v = (const float*)d_in[2];
  const float* w1  = (const float*)d_in[3];
  const float* cw  = (const float*)d_in[4];
  const float* cb  = (const float*)d_in[5];
  float* out = (float*)d_out;
  char* ws = (char*)d_ws;
  float* wfwdt        = (float*)(ws + WFWDT_OFF);
  float* pctt         = (float*)(ws + PCTT_OFF);
  _Float16* ffrag     = (_Float16*)(ws + FFRAG_OFF);
  _Float16* tbfr      = (_Float16*)(ws + TBFRAG_OFF);
  unsigned short* z   = (unsigned short*)(ws + Z_OFF);
  unsigned short* h   = (unsigned short*)(ws + H_OFF);
  float* oh0          = (float*)(ws + OH_OFF);
  float* oh1          = (float*)(ws + OH1_OFF);

  hipLaunchKernelGGL(k0_tables, dim3(2),   dim3(256), 0, stream, wfwdt, pctt, ffrag, tbfr);
  hipLaunchKernelGGL(k1_fwd,    dim3(512), dim3(256), 0, stream, x, wfwdt, ffrag, z);
  hipLaunchKernelGGL(k2_mlp1,   dim3(512), dim3(256), 0, stream, z, w0, b0v, h);
  hipLaunchKernelGGL(k3_mlp2,   dim3(512), dim3(256), 0, stream, h, w1, oh0, oh1);
  hipLaunchKernelGGL(k4_inv,    dim3(512), dim3(256), 0, stream, oh0, oh1, pctt, tbfr, x, cw, cb, out);
}